// Round 1
// baseline (62851.898 us; speedup 1.0000x reference)
//
#include <hip/hip_runtime.h>
#include <cstdint>
#include <cstddef>

// Problem constants (from reference setup_inputs)
constexpr int Hh = 51;      // hidden size
constexpr int Tt = 2048;    // timesteps
constexpr int Bb = 8192;    // batch
constexpr int NB = 64;      // batch elements per block (= lanes per wave)
constexpr int PADK = 52;    // padded h-row stride in floats (52*4=208 B, 16B aligned)
constexpr int NTHREADS = 512; // 8 waves

__device__ __forceinline__ float sigmoidf_(float x) {
    // 1/(1+e^-x); safe at both ends (exp->inf => rcp->0; exp->0 => 1)
    return __builtin_amdgcn_rcpf(1.0f + __expf(-x));
}

__device__ __forceinline__ float tanhf_(float x) {
    // tanh(x) = sign(x) * (1 - e^{-2|x|}) / (1 + e^{-2|x|}); e in (0,1], no overflow
    const float a = fabsf(x);
    const float e = __expf(-2.0f * a);
    const float r = (1.0f - e) * __builtin_amdgcn_rcpf(1.0f + e);
    return copysignf(r, x);
}

__device__ __forceinline__ float lstm_update(float ai, float af, float ag, float ao, float& c) {
    const float si = sigmoidf_(ai);
    const float sf = sigmoidf_(af);
    const float tg = tanhf_(ag);
    const float so = sigmoidf_(ao);
    c = fmaf(sf, c, si * tg);
    return so * tanhf_(c);
}

__global__ __launch_bounds__(NTHREADS)
void lstm_main(const float* __restrict__ xin,
               const float* __restrict__ Wih1, const float* __restrict__ Whh1,
               const float* __restrict__ bih1, const float* __restrict__ bhh1,
               const float* __restrict__ Wih2, const float* __restrict__ Whh2,
               const float* __restrict__ bih2, const float* __restrict__ bhh2,
               const float* __restrict__ Wlin, const float* __restrict__ blin,
               float* __restrict__ yout, int transposed)
{
    // h1/h2 double buffered: [2][NB][PADK]
    __shared__ __align__(16) float sh[4 * NB * PADK];
    float* h1buf = sh;
    float* h2buf = sh + 2 * NB * PADK;

    const int tid  = threadIdx.x;
    const int lane = tid & 63;
    const int wid  = __builtin_amdgcn_readfirstlane(tid >> 6); // wave-uniform wave id
    const int gb   = blockIdx.x * NB + lane;                   // global batch index

    // unit distribution: waves 1..3 get 7 units, others 6 (wave 0 lighter: it does the out-dot)
    const int ucount = 6 + ((wid >= 1 && wid <= 3) ? 1 : 0);
    const int ustart = 6 * wid + ((wid <= 1) ? 0 : (wid >= 4 ? 3 : wid - 1));

    // zero h buffers
    for (int i = tid; i < 4 * NB * PADK; i += NTHREADS) sh[i] = 0.0f;
    __syncthreads();

    // cell state in registers (static indexing via fully-unrolled pair loop)
    float c1r[8], c2r[8];
    #pragma unroll
    for (int i = 0; i < 8; ++i) { c1r[i] = 0.0f; c2r[i] = 0.0f; }

    const float bl = blin[0];

    for (int t = 0; t < Tt; ++t) {
        const int pr = t & 1;
        const int pw = pr ^ 1;
        float* __restrict__ h1r = h1buf + pr * NB * PADK;
        float* __restrict__ h1w = h1buf + pw * NB * PADK;
        float* __restrict__ h2r = h2buf + pr * NB * PADK;
        float* __restrict__ h2w = h2buf + pw * NB * PADK;

        const float x = transposed ? xin[(size_t)t * Bb + gb]
                                   : xin[(size_t)gb * Tt + t];
        const float* hb1 = h1r + lane * PADK;

        // ---------------- Layer 1 ----------------
        #pragma unroll
        for (int p = 0; p < 8; p += 2) {
            if (p < ucount) {
                const int dual = (p + 1 < ucount);
                const int j0 = ustart + p;
                const int j1 = dual ? (j0 + 1) : j0;

                const float* wr[8];
                float acc[8];
                #pragma unroll
                for (int u = 0; u < 2; ++u) {
                    const int j = u ? j1 : j0;
                    #pragma unroll
                    for (int g = 0; g < 4; ++g) {
                        const int row = g * Hh + j;
                        wr[4 * u + g]  = Whh1 + row * Hh;
                        acc[4 * u + g] = fmaf(x, Wih1[row], bih1[row] + bhh1[row]);
                    }
                }

                #pragma unroll 2
                for (int k = 0; k < 48; k += 4) {
                    const float4 hv = *(const float4*)(hb1 + k);
                    #pragma unroll
                    for (int r = 0; r < 8; ++r) {
                        acc[r] = fmaf(wr[r][k    ], hv.x, acc[r]);
                        acc[r] = fmaf(wr[r][k + 1], hv.y, acc[r]);
                        acc[r] = fmaf(wr[r][k + 2], hv.z, acc[r]);
                        acc[r] = fmaf(wr[r][k + 3], hv.w, acc[r]);
                    }
                }
                {
                    const float h48 = hb1[48], h49 = hb1[49], h50 = hb1[50];
                    #pragma unroll
                    for (int r = 0; r < 8; ++r) {
                        acc[r] = fmaf(wr[r][48], h48, acc[r]);
                        acc[r] = fmaf(wr[r][49], h49, acc[r]);
                        acc[r] = fmaf(wr[r][50], h50, acc[r]);
                    }
                }

                const float hn0 = lstm_update(acc[0], acc[1], acc[2], acc[3], c1r[p]);
                h1w[lane * PADK + j0] = hn0;
                if (dual) {
                    const float hn1 = lstm_update(acc[4], acc[5], acc[6], acc[7], c1r[p + 1]);
                    h1w[lane * PADK + j1] = hn1;
                }
            }
        }
        __syncthreads();

        // ---------------- Layer 2 ----------------
        const float* ha  = h1w + lane * PADK;  // new h1 (input to layer 2)
        const float* hbv = h2r + lane * PADK;  // old h2
        #pragma unroll
        for (int p = 0; p < 8; p += 2) {
            if (p < ucount) {
                const int dual = (p + 1 < ucount);
                const int j0 = ustart + p;
                const int j1 = dual ? (j0 + 1) : j0;

                const float* wa[8];
                const float* wb[8];
                float acc[8];
                #pragma unroll
                for (int u = 0; u < 2; ++u) {
                    const int j = u ? j1 : j0;
                    #pragma unroll
                    for (int g = 0; g < 4; ++g) {
                        const int row = g * Hh + j;
                        wa[4 * u + g]  = Wih2 + row * Hh;
                        wb[4 * u + g]  = Whh2 + row * Hh;
                        acc[4 * u + g] = bih2[row] + bhh2[row];
                    }
                }

                #pragma unroll 2
                for (int k = 0; k < 48; k += 4) {
                    const float4 va = *(const float4*)(ha + k);
                    const float4 vb = *(const float4*)(hbv + k);
                    #pragma unroll
                    for (int r = 0; r < 8; ++r) {
                        acc[r] = fmaf(wa[r][k    ], va.x, acc[r]);
                        acc[r] = fmaf(wa[r][k + 1], va.y, acc[r]);
                        acc[r] = fmaf(wa[r][k + 2], va.z, acc[r]);
                        acc[r] = fmaf(wa[r][k + 3], va.w, acc[r]);
                        acc[r] = fmaf(wb[r][k    ], vb.x, acc[r]);
                        acc[r] = fmaf(wb[r][k + 1], vb.y, acc[r]);
                        acc[r] = fmaf(wb[r][k + 2], vb.z, acc[r]);
                        acc[r] = fmaf(wb[r][k + 3], vb.w, acc[r]);
                    }
                }
                {
                    const float a48 = ha[48],  a49 = ha[49],  a50 = ha[50];
                    const float b48 = hbv[48], b49 = hbv[49], b50 = hbv[50];
                    #pragma unroll
                    for (int r = 0; r < 8; ++r) {
                        acc[r] = fmaf(wa[r][48], a48, acc[r]);
                        acc[r] = fmaf(wa[r][49], a49, acc[r]);
                        acc[r] = fmaf(wa[r][50], a50, acc[r]);
                        acc[r] = fmaf(wb[r][48], b48, acc[r]);
                        acc[r] = fmaf(wb[r][49], b49, acc[r]);
                        acc[r] = fmaf(wb[r][50], b50, acc[r]);
                    }
                }

                const float hn0 = lstm_update(acc[0], acc[1], acc[2], acc[3], c2r[p]);
                h2w[lane * PADK + j0] = hn0;
                if (dual) {
                    const float hn1 = lstm_update(acc[4], acc[5], acc[6], acc[7], c2r[p + 1]);
                    h2w[lane * PADK + j1] = hn1;
                }
            }
        }
        __syncthreads();

        // ---------------- Output projection (wave 0) ----------------
        if (wid == 0) {
            const float* hy = h2w + lane * PADK;
            float acc = bl;
            #pragma unroll 2
            for (int k = 0; k < 48; k += 4) {
                const float4 hv = *(const float4*)(hy + k);
                acc = fmaf(Wlin[k    ], hv.x, acc);
                acc = fmaf(Wlin[k + 1], hv.y, acc);
                acc = fmaf(Wlin[k + 2], hv.z, acc);
                acc = fmaf(Wlin[k + 3], hv.w, acc);
            }
            acc = fmaf(Wlin[48], hy[48], acc);
            acc = fmaf(Wlin[49], hy[49], acc);
            acc = fmaf(Wlin[50], hy[50], acc);
            if (transposed) yout[(size_t)t * Bb + gb] = acc;
            else            yout[(size_t)gb * Tt + t] = acc;
        }
        // no barrier needed here: out-dot reads h2w; next L1 phase touches only h1/c1,
        // and the next L2-phase h2 write targets the *other* h2 buffer, after a barrier.
    }
}

// Generic tiled transpose: src[R][C] -> dst[C][R]; R, C multiples of 64.
__global__ __launch_bounds__(512)
void transpose_k(const float* __restrict__ src, float* __restrict__ dst, int R, int C)
{
    __shared__ float tile[64][65];
    const int c0 = blockIdx.x * 64;
    const int r0 = blockIdx.y * 64;
    const int tx = threadIdx.x;
    const int ty = threadIdx.y;
    #pragma unroll
    for (int i = 0; i < 64; i += 8) {
        tile[ty + i][tx] = src[(size_t)(r0 + ty + i) * C + (c0 + tx)];
    }
    __syncthreads();
    #pragma unroll
    for (int i = 0; i < 64; i += 8) {
        dst[(size_t)(c0 + ty + i) * R + (r0 + tx)] = tile[tx][ty + i];
    }
}

extern "C" void kernel_launch(void* const* d_in, const int* in_sizes, int n_in,
                              void* d_out, int out_size, void* d_ws, size_t ws_size,
                              hipStream_t stream)
{
    const float* input = (const float*)d_in[0];
    const float* Wih1  = (const float*)d_in[1];
    const float* Whh1  = (const float*)d_in[2];
    const float* bih1  = (const float*)d_in[3];
    const float* bhh1  = (const float*)d_in[4];
    const float* Wih2  = (const float*)d_in[5];
    const float* Whh2  = (const float*)d_in[6];
    const float* bih2  = (const float*)d_in[7];
    const float* bhh2  = (const float*)d_in[8];
    const float* Wlin  = (const float*)d_in[9];
    const float* blin  = (const float*)d_in[10];
    float* out = (float*)d_out;

    const size_t elems = (size_t)Bb * Tt;
    const size_t need  = 2 * elems * sizeof(float);
    const bool usews   = (ws_size >= need);

    if (usews) {
        float* inT  = (float*)d_ws;
        float* outT = inT + elems;
        // input [B][T] -> inT [T][B]
        transpose_k<<<dim3(Tt / 64, Bb / 64), dim3(64, 8), 0, stream>>>(input, inT, Bb, Tt);
        lstm_main<<<dim3(Bb / NB), dim3(NTHREADS), 0, stream>>>(
            inT, Wih1, Whh1, bih1, bhh1, Wih2, Whh2, bih2, bhh2, Wlin, blin, outT, 1);
        // outT [T][B] -> out [B][T]
        transpose_k<<<dim3(Bb / 64, Tt / 64), dim3(64, 8), 0, stream>>>(outT, out, Tt, Bb);
    } else {
        lstm_main<<<dim3(Bb / NB), dim3(NTHREADS), 0, stream>>>(
            input, Wih1, Whh1, bih1, bhh1, Wih2, Whh2, bih2, bhh2, Wlin, blin, out, 0);
    }
}